// Round 15
// baseline (209.656 us; speedup 1.0000x reference)
//
#include <hip/hip_runtime.h>
#include <hip/hip_bf16.h>
#include <cstdint>

#define B_  4096
#define T_  20
#define F_  32
#define E_  128
#define H_  2
#define D_  64
#define L_  3
#define HD_ 128
#define EPS_ 1e-5f

typedef __bf16 bfv8 __attribute__((ext_vector_type(8)));
typedef __bf16 bfv4 __attribute__((ext_vector_type(4)));
typedef float  f32x4 __attribute__((ext_vector_type(4)));

__device__ __forceinline__ f32x4 mfma16(bfv8 a, bfv8 b, f32x4 c) {
    return __builtin_amdgcn_mfma_f32_16x16x32_bf16(a, b, c, 0, 0, 0);
}

__device__ __forceinline__ void gload16(const __bf16* g, __bf16* l) {
    __builtin_amdgcn_global_load_lds(
        (const __attribute__((address_space(1))) void*)(g),
        (__attribute__((address_space(3))) void*)(l),
        16, 0, 0);
}

// ---------------------------------------------------------------------------
// 0. PREP kernel: attention-weight pack + W1 transpose + embeddings.
//    [0,96): pkw | [96,1120): W1t | [1120,3168): token emb | [3168,7136): field
// ---------------------------------------------------------------------------
__device__ void transpose_pack_body(const float* __restrict__ in,
                                    __bf16* __restrict__ out,
                                    int K, int N, int bx, int by)
{
    __shared__ float t[64][65];
    int k0 = bx * 64, n0 = by * 64;
    int r = threadIdx.x >> 4, c = (threadIdx.x & 15) * 4;
    for (int rr = r; rr < 64; rr += 16) {
        float4 v = *(const float4*)&in[(int64_t)(k0 + rr) * N + n0 + c];
        t[rr][c] = v.x; t[rr][c + 1] = v.y; t[rr][c + 2] = v.z; t[rr][c + 3] = v.w;
    }
    __syncthreads();
    for (int rr = r; rr < 64; rr += 16) {
        bfv4 o;
        o[0] = (__bf16)t[c + 0][rr];
        o[1] = (__bf16)t[c + 1][rr];
        o[2] = (__bf16)t[c + 2][rr];
        o[3] = (__bf16)t[c + 3][rr];
        *(bfv4*)&out[(int64_t)(n0 + rr) * K + k0 + c] = o;
    }
}

__global__ __launch_bounds__(256) void prep_kernel(
    const float* __restrict__ Wq, const float* __restrict__ Wk,
    const float* __restrict__ Wv, const float* __restrict__ Wres,
    __bf16* __restrict__ pkw,
    const float* __restrict__ dW1, __bf16* __restrict__ W1t,
    const int* __restrict__ tokens, const float* __restrict__ word_emb,
    const float* __restrict__ W_tok,
    const int* __restrict__ field_ids, const float* __restrict__ field_tables,
    __bf16* __restrict__ embbf)
{
    int id = blockIdx.x;
    if (id < 96) {
        int mi = id >> 3, tile = id & 7;
        int l = mi >> 2, p = mi & 3;
        const float* Wb = (p == 0 ? Wq : p == 1 ? Wk : p == 2 ? Wv : Wres) + l * 16384;
        int tid = threadIdx.x;
        int ks = tid >> 6, lane = tid & 63;
        int l15 = lane & 15, lgg = lane >> 4;
        const float* src = Wb + (ks * 32 + lgg * 8) * HD_ + tile * 16 + l15;
        __bf16* dst = pkw + (int64_t)mi * 16384 + ((tile * 4 + ks) * 64 + lane) * 8;
        #pragma unroll
        for (int t = 0; t < 8; t++) dst[t] = (__bf16)src[t * HD_];
    } else if (id < 1120) {
        int t = id - 96;
        transpose_pack_body(dW1, W1t, 4096, 1024, t & 63, t >> 6);
    } else if (id < 3168) {
        __shared__ float m[2][304];
        int half = threadIdx.x >> 7, t7 = threadIdx.x & 127;
        int b = (id - 1120) * 2 + half;
        float a0 = 0.f, a1 = 0.f, a2 = 0.f;
        const int* tb = tokens + b * T_;
        for (int t = 0; t < T_; t++) {
            const float* row = word_emb + (int64_t)tb[t] * 300;
            a0 += row[t7];
            a1 += row[t7 + 128];
            if (t7 < 44) a2 += row[t7 + 256];
        }
        m[half][t7]       = a0 * (1.f / T_);
        m[half][t7 + 128] = a1 * (1.f / T_);
        if (t7 < 44) m[half][t7 + 256] = a2 * (1.f / T_);
        __syncthreads();
        float s = 0.f;
        for (int e = 0; e < 300; e++) s = fmaf(m[half][e], W_tok[e * E_ + t7], s);
        embbf[(int64_t)b * (F_ * E_) + t7] = (__bf16)s;
    } else {
        int64_t base = (int64_t)(id - 3168) * 1024 + threadIdx.x;
        #pragma unroll
        for (int u = 0; u < 4; u++) {
            int64_t idx = base + u * 256;
            int c = (int)(idx & 31);
            int64_t tmp = idx >> 5;
            int f = (int)(tmp % 31);
            int b = (int)(tmp / 31);
            int ident = field_ids[b * 31 + f];
            const float4* src = (const float4*)field_tables;
            float4 val = src[(int64_t)(f * 1000 + ident) * 32 + c];
            bfv4 o;
            o[0] = (__bf16)val.x; o[1] = (__bf16)val.y;
            o[2] = (__bf16)val.z; o[3] = (__bf16)val.w;
            *(bfv4*)&embbf[(int64_t)b * 4096 + (1 + f) * 128 + c * 4] = o;
        }
    }
}

// ---------------------------------------------------------------------------
// 3b. 128x64-tile bf16 MFMA GEMM (W2).
// ---------------------------------------------------------------------------
template <int OUTBF, int EPI>
__global__ __launch_bounds__(256) void gemm_bt_bf16(
    const __bf16* __restrict__ A, const __bf16* __restrict__ Bt,
    void* __restrict__ Cout, int M, int N, int K,
    const float* __restrict__ gp, const float* __restrict__ bp,
    const float* __restrict__ mp, const float* __restrict__ vp)
{
    __shared__ __bf16 As[128 * 64];
    __shared__ __bf16 Bs[64 * 64];
    const int tid = threadIdx.x;
    const int wid = tid >> 6, lane = tid & 63;
    const int l15 = lane & 15, lg = lane >> 4;
    const int wr = wid >> 1, wc = wid & 1;
    const int bm = blockIdx.x, bn = blockIdx.y;

    const int srow = lane >> 3, sp = lane & 7;
    const __bf16* Ag[4]; const __bf16* Bg[2];
    __bf16* Ad[4]; __bf16* Bd[2];
    #pragma unroll
    for (int ga = 0; ga < 4; ga++) {
        int row = wid * 32 + ga * 8 + srow;
        int slot = sp ^ (row & 7);
        Ag[ga] = A + (int64_t)(bm * 128 + row) * K + slot * 8;
        Ad[ga] = &As[(wid * 32 + ga * 8) * 64];
    }
    #pragma unroll
    for (int gb = 0; gb < 2; gb++) {
        int row = wid * 16 + gb * 8 + srow;
        int slot = sp ^ (row & 7);
        Bg[gb] = Bt + (int64_t)(bn * 64 + row) * K + slot * 8;
        Bd[gb] = &Bs[(wid * 16 + gb * 8) * 64];
    }

    int ar[2][4], br2[2][2];
    #pragma unroll
    for (int ks = 0; ks < 2; ks++) {
        #pragma unroll
        for (int mi = 0; mi < 4; mi++) {
            int row = wr * 64 + mi * 16 + l15;
            ar[ks][mi] = row * 64 + (((ks * 4 + lg) ^ (row & 7)) * 8);
        }
        #pragma unroll
        for (int ni = 0; ni < 2; ni++) {
            int row = wc * 32 + ni * 16 + l15;
            br2[ks][ni] = row * 64 + (((ks * 4 + lg) ^ (row & 7)) * 8);
        }
    }

    f32x4 acc[4][2];
    #pragma unroll
    for (int mi = 0; mi < 4; mi++)
        #pragma unroll
        for (int ni = 0; ni < 2; ni++) acc[mi][ni] = (f32x4){0.f, 0.f, 0.f, 0.f};

    for (int k0 = 0; k0 < K; k0 += 64) {
        #pragma unroll
        for (int ga = 0; ga < 4; ga++) gload16(Ag[ga] + k0, Ad[ga]);
        #pragma unroll
        for (int gb = 0; gb < 2; gb++) gload16(Bg[gb] + k0, Bd[gb]);
        __syncthreads();
        #pragma unroll
        for (int ks = 0; ks < 2; ks++) {
            bfv8 af[4], bf2[2];
            #pragma unroll
            for (int mi = 0; mi < 4; mi++) af[mi] = *(const bfv8*)&As[ar[ks][mi]];
            #pragma unroll
            for (int ni = 0; ni < 2; ni++) bf2[ni] = *(const bfv8*)&Bs[br2[ks][ni]];
            #pragma unroll
            for (int mi = 0; mi < 4; mi++)
                #pragma unroll
                for (int ni = 0; ni < 2; ni++)
                    acc[mi][ni] = mfma16(af[mi], bf2[ni], acc[mi][ni]);
        }
        __syncthreads();
    }

    float inv[2], sh[2];
    #pragma unroll
    for (int ni = 0; ni < 2; ni++) {
        int col = bn * 64 + wc * 32 + ni * 16 + l15;
        if constexpr (EPI == 0) {
            float iv = rsqrtf(vp[col] + EPS_) * gp[col];
            inv[ni] = iv;
            sh[ni] = bp[col] - mp[col] * iv;
        } else {
            inv[ni] = 1.f;
            sh[ni] = bp[col];
        }
    }
    #pragma unroll
    for (int mi = 0; mi < 4; mi++)
        #pragma unroll
        for (int ni = 0; ni < 2; ni++) {
            int col = bn * 64 + wc * 32 + ni * 16 + l15;
            #pragma unroll
            for (int r = 0; r < 4; r++) {
                int row = bm * 128 + wr * 64 + mi * 16 + lg * 4 + r;
                float y = fmaf(acc[mi][ni][r], inv[ni], sh[ni]);
                if constexpr (EPI == 0) y = fmaxf(y, 0.f);
                if constexpr (OUTBF)
                    ((__bf16*)Cout)[(int64_t)row * N + col] = (__bf16)y;
                else
                    ((float*)Cout)[(int64_t)row * N + col] = y;
            }
        }
}

// ---------------------------------------------------------------------------
// 3c. W3 GEMM + head, fused. 128x128 tile, 4 waves, K=512, grid=32.
// ---------------------------------------------------------------------------
__global__ __launch_bounds__(256) void gemm_w3_head_kernel(
    const __bf16* __restrict__ A, const __bf16* __restrict__ Bt,
    const float* __restrict__ b3, const float* __restrict__ Wl,
    const float* __restrict__ attnp, const float* __restrict__ bl,
    float* __restrict__ out)
{
    __shared__ __bf16 As[128 * 64];
    __shared__ __bf16 Bs[128 * 64];
    __shared__ float  hp[128][2];
    const int tid = threadIdx.x;
    const int wid = tid >> 6, lane = tid & 63;
    const int l15 = lane & 15, lg = lane >> 4;
    const int wr = wid >> 1, wc = wid & 1;
    const int bm = blockIdx.x;
    const int K = 512;

    const int srow = lane >> 3, sp = lane & 7;
    const __bf16* Ag[4]; const __bf16* Bg[4];
    __bf16* Ad[4]; __bf16* Bd[4];
    #pragma unroll
    for (int ga = 0; ga < 4; ga++) {
        int row = wid * 32 + ga * 8 + srow;
        int slot = sp ^ (row & 7);
        Ag[ga] = A  + (int64_t)(bm * 128 + row) * K + slot * 8;
        Bg[ga] = Bt + (int64_t)row * K + slot * 8;
        Ad[ga] = &As[(wid * 32 + ga * 8) * 64];
        Bd[ga] = &Bs[(wid * 32 + ga * 8) * 64];
    }

    int ar[2][4], br[2][4];
    #pragma unroll
    for (int ks = 0; ks < 2; ks++) {
        #pragma unroll
        for (int mi = 0; mi < 4; mi++) {
            int rowa = wr * 64 + mi * 16 + l15;
            ar[ks][mi] = rowa * 64 + (((ks * 4 + lg) ^ (rowa & 7)) * 8);
            int rowb = wc * 64 + mi * 16 + l15;
            br[ks][mi] = rowb * 64 + (((ks * 4 + lg) ^ (rowb & 7)) * 8);
        }
    }

    f32x4 acc[4][4];
    #pragma unroll
    for (int mi = 0; mi < 4; mi++)
        #pragma unroll
        for (int ni = 0; ni < 4; ni++) acc[mi][ni] = (f32x4){0.f, 0.f, 0.f, 0.f};

    for (int k0 = 0; k0 < K; k0 += 64) {
        #pragma unroll
        for (int ga = 0; ga < 4; ga++) gload16(Ag[ga] + k0, Ad[ga]);
        #pragma unroll
        for (int ga = 0; ga < 4; ga++) gload16(Bg[ga] + k0, Bd[ga]);
        __syncthreads();
        #pragma unroll
        for (int ks = 0; ks < 2; ks++) {
            bfv8 af[4], bf[4];
            #pragma unroll
            for (int mi = 0; mi < 4; mi++) af[mi] = *(const bfv8*)&As[ar[ks][mi]];
            #pragma unroll
            for (int ni = 0; ni < 4; ni++) bf[ni] = *(const bfv8*)&Bs[br[ks][ni]];
            #pragma unroll
            for (int mi = 0; mi < 4; mi++)
                #pragma unroll
                for (int ni = 0; ni < 4; ni++)
                    acc[mi][ni] = mfma16(af[mi], bf[ni], acc[mi][ni]);
        }
        __syncthreads();
    }

    float wl[4], bb[4];
    #pragma unroll
    for (int ni = 0; ni < 4; ni++) {
        int col = wc * 64 + ni * 16 + l15;
        wl[ni] = Wl[4096 + col];
        bb[ni] = b3[col];
    }
    #pragma unroll
    for (int mi = 0; mi < 4; mi++) {
        #pragma unroll
        for (int r = 0; r < 4; r++) {
            float p = (acc[mi][0][r] + bb[0]) * wl[0]
                    + (acc[mi][1][r] + bb[1]) * wl[1]
                    + (acc[mi][2][r] + bb[2]) * wl[2]
                    + (acc[mi][3][r] + bb[3]) * wl[3];
            p += __shfl_xor(p, 1);
            p += __shfl_xor(p, 2);
            p += __shfl_xor(p, 4);
            p += __shfl_xor(p, 8);
            if (l15 == 0) hp[wr * 64 + mi * 16 + lg * 4 + r][wc] = p;
        }
    }
    __syncthreads();
    if (tid < 128) {
        int64_t b0 = (int64_t)bm * 128 + tid;
        float s = hp[tid][0] + hp[tid][1] + attnp[b0] + bl[0];
        out[b0] = 1.f / (1.f + __expf(-s));
    }
}

// ---------------------------------------------------------------------------
// MEGA kernel: [0,256) W1 GEMM | [256,400) W2t/W3t transpose |
//              [400,2448) fused 3-layer attention (head -> attnp).
//              T5: s_setprio(1) around attn MFMA clusters (m191: +4-7% attn).
// ---------------------------------------------------------------------------
#define W1_BLOCKS_ 256
#define TR_BLOCKS_ 144

__global__ __launch_bounds__(512, 4) void mega_w1_attn_kernel(
    const __bf16* __restrict__ embbf, const __bf16* __restrict__ W1t,
    __bf16* __restrict__ h1bf,
    const float* __restrict__ bn1g, const float* __restrict__ bn1b,
    const float* __restrict__ bn1m, const float* __restrict__ bn1v,
    const __bf16* __restrict__ pkw,
    const float* __restrict__ lng, const float* __restrict__ lnb,
    const float* __restrict__ Wl, float* __restrict__ attnp,
    const float* __restrict__ dW2, __bf16* __restrict__ W2t,
    const float* __restrict__ dW3, __bf16* __restrict__ W3t)
{
    __shared__ __bf16 smem[8192 * 4 + 4096];
    __shared__ float  part[2][128];

    const int tid = threadIdx.x;
    const int wid = tid >> 6, lane = tid & 63;
    const int l15 = lane & 15, lg = lane >> 4;

    if (blockIdx.x < W1_BLOCKS_) {
        // ================= W1 GEMM branch: 128x128 tile, 8 waves ===========
        __bf16* As = smem;
        __bf16* Bs = smem + 8192;
        const int wr = wid >> 2, wc = wid & 3;
        const int bm = blockIdx.x >> 3, bn = blockIdx.x & 7;
        const int K = 4096, N = 1024;

        const int srow = lane >> 3, sp = lane & 7;
        const __bf16* Ag[2]; const __bf16* Bg[2];
        __bf16* Ad[2]; __bf16* Bd[2];
        #pragma unroll
        for (int c = 0; c < 2; c++) {
            int rbase = wid * 16 + c * 8;
            int row = rbase + srow;
            int slot = sp ^ (row & 7);
            Ag[c] = embbf + (int64_t)(bm * 128 + row) * K + slot * 8;
            Bg[c] = W1t   + (int64_t)(bn * 128 + row) * K + slot * 8;
            Ad[c] = &As[rbase * 64];
            Bd[c] = &Bs[rbase * 64];
        }

        int ar[2][4], br[2][2];
        #pragma unroll
        for (int ks = 0; ks < 2; ks++) {
            #pragma unroll
            for (int mi = 0; mi < 4; mi++) {
                int rowa = wr * 64 + mi * 16 + l15;
                ar[ks][mi] = rowa * 64 + (((ks * 4 + lg) ^ (rowa & 7)) * 8);
            }
            #pragma unroll
            for (int ni = 0; ni < 2; ni++) {
                int rowb = wc * 32 + ni * 16 + l15;
                br[ks][ni] = rowb * 64 + (((ks * 4 + lg) ^ (rowb & 7)) * 8);
            }
        }

        f32x4 acc[4][2];
        #pragma unroll
        for (int mi = 0; mi < 4; mi++)
            #pragma unroll
            for (int ni = 0; ni < 2; ni++) acc[mi][ni] = (f32x4){0.f, 0.f, 0.f, 0.f};

        for (int k0 = 0; k0 < K; k0 += 64) {
            #pragma unroll
            for (int c = 0; c < 2; c++) gload16(Ag[c] + k0, Ad[c]);
            #pragma unroll
            for (int c = 0; c < 2; c++) gload16(Bg[c] + k0, Bd[c]);
            __syncthreads();
            #pragma unroll
            for (int ks = 0; ks < 2; ks++) {
                bfv8 af[4], bf[2];
                #pragma unroll
                for (int mi = 0; mi < 4; mi++) af[mi] = *(const bfv8*)&As[ar[ks][mi]];
                #pragma unroll
                for (int ni = 0; ni < 2; ni++) bf[ni] = *(const bfv8*)&Bs[br[ks][ni]];
                #pragma unroll
                for (int mi = 0; mi < 4; mi++)
                    #pragma unroll
                    for (int ni = 0; ni < 2; ni++)
                        acc[mi][ni] = mfma16(af[mi], bf[ni], acc[mi][ni]);
            }
            __syncthreads();
        }

        float inv[2], sh[2];
        #pragma unroll
        for (int ni = 0; ni < 2; ni++) {
            int col = bn * 128 + wc * 32 + ni * 16 + l15;
            float iv = rsqrtf(bn1v[col] + EPS_) * bn1g[col];
            inv[ni] = iv;
            sh[ni] = bn1b[col] - bn1m[col] * iv;
        }
        #pragma unroll
        for (int mi = 0; mi < 4; mi++)
            #pragma unroll
            for (int ni = 0; ni < 2; ni++) {
                int col = bn * 128 + wc * 32 + ni * 16 + l15;
                #pragma unroll
                for (int r = 0; r < 4; r++) {
                    int row = bm * 128 + wr * 64 + mi * 16 + lg * 4 + r;
                    float y = fmaxf(fmaf(acc[mi][ni][r], inv[ni], sh[ni]), 0.f);
                    h1bf[(int64_t)row * N + col] = (__bf16)y;
                }
            }
        return;
    }

    if (blockIdx.x < W1_BLOCKS_ + TR_BLOCKS_) {
        // ================= W2t / W3t transpose branch (512 threads) ========
        float* t = (float*)smem;
        int tb = blockIdx.x - W1_BLOCKS_;
        const float* in; __bf16* outp; int K, N, bx, by;
        if (tb < 128) { in = dW2; outp = W2t; K = 1024; N = 512; bx = tb & 15; by = tb >> 4; }
        else          { tb -= 128; in = dW3; outp = W3t; K = 512; N = 128; bx = tb & 7; by = tb >> 3; }
        int k0 = bx * 64, n0 = by * 64;
        int r = tid >> 4, c = (tid & 15) * 4;
        for (int rr = r; rr < 64; rr += 32) {
            float4 v = *(const float4*)&in[(int64_t)(k0 + rr) * N + n0 + c];
            t[rr * 65 + c] = v.x; t[rr * 65 + c + 1] = v.y;
            t[rr * 65 + c + 2] = v.z; t[rr * 65 + c + 3] = v.w;
        }
        __syncthreads();
        for (int rr = r; rr < 64; rr += 32) {
            bfv4 o;
            o[0] = (__bf16)t[(c + 0) * 65 + rr];
            o[1] = (__bf16)t[(c + 1) * 65 + rr];
            o[2] = (__bf16)t[(c + 2) * 65 + rr];
            o[3] = (__bf16)t[(c + 3) * 65 + rr];
            *(bfv4*)&outp[(int64_t)(n0 + rr) * K + k0 + c] = o;
        }
        return;
    }

    // ================= attention branch (round-10 verified body + T5) ======
    const int ablk = blockIdx.x - (W1_BLOCKS_ + TR_BLOCKS_);
    __bf16* xs  = smem;
    __bf16* qf  = smem + 8192;
    __bf16* kf  = smem + 16384;
    __bf16* vtf = smem + 24576;
    __bf16* pf  = smem + 32768;

    const int arow = wid >> 2, h = (wid >> 1) & 1, qh = wid & 1;
    const int q = qh * 16 + l15;
    const int half = (lg & 1) * 4;

    {
        const __bf16* src = embbf + (int64_t)ablk * 8192;
        #pragma unroll
        for (int u = 0; u < 2; u++) {
            int g = u * 512 + tid;
            int ln = g & 63;
            int fld = (((g >> 8) & 1) << 4) + (ln & 15);
            int e0 = ((g >> 6) & 3) * 32 + (ln >> 4) * 8;
            int br = g >> 9;
            bfv8 v = *(const bfv8*)&src[br * 4096 + fld * 128 + e0];
            *(bfv8*)&xs[g * 8] = v;
        }
    }
    __syncthreads();

    float head_partial = 0.f;

    for (int l = 0; l < L_; l++) {
        #pragma unroll 1
        for (int cc = 0; cc < 3; cc++) {
            const int col = wid * 3 + cc;
            const int mat = col >> 3, m = col & 7;
            const __bf16* W = pkw + (l * 4 + mat) * 16384;
            bfv8 wf[4];
            #pragma unroll
            for (int ks = 0; ks < 4; ks++)
                wf[ks] = *(const bfv8*)(W + ((m * 4 + ks) * 64 + lane) * 8);
            f32x4 pc[4];
            #pragma unroll
            for (int i = 0; i < 4; i++) pc[i] = (f32x4){0.f, 0.f, 0.f, 0.f};

            __builtin_amdgcn_s_setprio(1);
            if (mat == 2) {
                #pragma unroll
                for (int i = 0; i < 4; i++) {
                    int gbase = ((i >> 1) * 8 + (i & 1) * 4) * 64;
                    #pragma unroll
                    for (int ks = 0; ks < 4; ks++) {
                        bfv8 xv = *(const bfv8*)&xs[(gbase + ks * 64 + lane) * 8];
                        pc[i] = mfma16(xv, wf[ks], pc[i]);
                    }
                }
            } else {
                #pragma unroll
                for (int i = 0; i < 4; i++) {
                    int gbase = ((i >> 1) * 8 + (i & 1) * 4) * 64;
                    #pragma unroll
                    for (int ks = 0; ks < 4; ks++) {
                        bfv8 xv = *(const bfv8*)&xs[(gbase + ks * 64 + lane) * 8];
                        pc[i] = mfma16(wf[ks], xv, pc[i]);
                    }
                }
            }
            __builtin_amdgcn_s_setprio(0);

            if (mat == 0) {
                const int ln2 = ((((m << 1) + (lg >> 1)) & 3) << 4) + l15;
                #pragma unroll
                for (int i = 0; i < 4; i++) {
                    bfv4 v4;
                    #pragma unroll
                    for (int r = 0; r < 4; r++) v4[r] = (__bf16)(pc[i][r] * 0.125f);
                    int g = ((i >> 1) * 8 + (i & 1) * 4 + (m >> 1)) * 64 + ln2;
                    *(bfv4*)&qf[g * 8 + half] = v4;
                }
            } else if (mat == 1) {
                const int ln2 = ((((m << 1) + (lg >> 1)) & 3) << 4) + l15;
                #pragma unroll
                for (int i = 0; i < 4; i++) {
                    bfv4 v4;
                    #pragma unroll
                    for (int r = 0; r < 4; r++) v4[r] = (__bf16)pc[i][r];
                    int g = ((i >> 1) * 8 + (i & 1) * 4 + (m >> 1)) * 64 + ln2;
                    *(bfv4*)&kf[g * 8 + half] = v4;
                }
            } else {
                #pragma unroll
                for (int i = 0; i < 4; i++) {
                    bfv4 v4;
                    #pragma unroll
                    for (int r = 0; r < 4; r++) v4[r] = (__bf16)pc[i][r];
                    int lnv = ((((i & 1) * 2 + (lg >> 1)) & 3) << 4) + l15;
                    int g = ((i >> 1) * 8 + m) * 64 + lnv;
                    *(bfv4*)&vtf[g * 8 + half] = v4;
                }
            }
        }
        __syncthreads();   // barrier A

        const __bf16* Wr = pkw + (l * 4 + 3) * 16384;
        bfv8 wr0[4], wr1[4], wr2[4], wr3[4];
        #pragma unroll
        for (int ks = 0; ks < 4; ks++) {
            wr0[ks] = *(const bfv8*)(Wr + (((h * 4 + 0) * 4 + ks) * 64 + lane) * 8);
            wr1[ks] = *(const bfv8*)(Wr + (((h * 4 + 1) * 4 + ks) * 64 + lane) * 8);
            wr2[ks] = *(const bfv8*)(Wr + (((h * 4 + 2) * 4 + ks) * 64 + lane) * 8);
            wr3[ks] = *(const bfv8*)(Wr + (((h * 4 + 3) * 4 + ks) * 64 + lane) * 8);
        }

        f32x4 sc2[2] = {(f32x4){0.f, 0.f, 0.f, 0.f}, (f32x4){0.f, 0.f, 0.f, 0.f}};
        __builtin_amdgcn_s_setprio(1);
        #pragma unroll
        for (int ksp = 0; ksp < 2; ksp++) {
            int dks = h * 2 + ksp;
            bfv8 qb = *(const bfv8*)&qf[((arow * 8 + qh * 4 + dks) * 64 + lane) * 8];
            #pragma unroll
            for (int km = 0; km < 2; km++) {
                bfv8 kb = *(const bfv8*)&kf[((arow * 8 + km * 4 + dks) * 64 + lane) * 8];
                sc2[km] = mfma16(kb, qb, sc2[km]);
            }
        }

        f32x4 macc[4];
        {
            bfv8 xr[4];
            #pragma unroll
            for (int ks = 0; ks < 4; ks++)
                xr[ks] = *(const bfv8*)&xs[((arow * 8 + qh * 4 + ks) * 64 + lane) * 8];
            macc[0] = (f32x4){0.f, 0.f, 0.f, 0.f};
            macc[1] = (f32x4){0.f, 0.f, 0.f, 0.f};
            macc[2] = (f32x4){0.f, 0.f, 0.f, 0.f};
            macc[3] = (f32x4){0.f, 0.f, 0.f, 0.f};
            #pragma unroll
            for (int ks = 0; ks < 4; ks++) {
                macc[0] = mfma16(wr0[ks], xr[ks], macc[0]);
                macc[1] = mfma16(wr1[ks], xr[ks], macc[1]);
                macc[2] = mfma16(wr2[ks], xr[ks], macc[2]);
                macc[3] = mfma16(wr3[ks], xr[ks], macc[3]);
            }
        }
        __builtin_amdgcn_s_setprio(0);

        float mx = -1e30f;
        #pragma unroll
        for (int km = 0; km < 2; km++)
            #pragma unroll
            for (int r = 0; r < 4; r++) mx = fmaxf(mx, sc2[km][r]);
        mx = fmaxf(mx, __shfl_xor(mx, 16));
        mx = fmaxf(mx, __shfl_xor(mx, 32));
        float pv[2][4];
        float sum = 0.f;
        #pragma unroll
        for (int km = 0; km < 2; km++)
            #pragma unroll
            for (int r = 0; r < 4; r++) {
                float e = __expf(sc2[km][r] - mx);
                pv[km][r] = e; sum += e;
            }
        sum += __shfl_xor(sum, 16);
        sum += __shfl_xor(sum, 32);
        float inv = 1.f / sum;

        __bf16* pw = pf + wid * 512;
        #pragma unroll
        for (int km = 0; km < 2; km++) {
            int ln2 = (((km * 2 + (lg >> 1)) & 3) << 4) + l15;
            bfv4 v4;
            #pragma unroll
            for (int r = 0; r < 4; r++) v4[r] = (__bf16)(pv[km][r] * inv);
            *(bfv4*)&pw[ln2 * 8 + half] = v4;
        }
        bfv8 pb = *(const bfv8*)&pw[lane * 8];
        __builtin_amdgcn_s_setprio(1);
        #pragma unroll
        for (int dm = 0; dm < 4; dm++) {
            bfv8 va = *(const bfv8*)&vtf[((arow * 8 + h * 4 + dm) * 64 + lane) * 8];
            macc[dm] = mfma16(va, pb, macc[dm]);
        }
        __builtin_amdgcn_s_setprio(0);

        float yv[4][4];
        float s1 = 0.f, s2 = 0.f;
        #pragma unroll
        for (int dm = 0; dm < 4; dm++) {
            #pragma unroll
            for (int r = 0; r < 4; r++) {
                float v = fmaxf(macc[dm][r], 0.f);
                yv[dm][r] = v;
                s1 += v; s2 += v * v;
            }
        }
        s1 += __shfl_xor(s1, 16); s1 += __shfl_xor(s1, 32);
        s2 += __shfl_xor(s2, 16); s2 += __shfl_xor(s2, 32);
        if (lg == 0) { part[arow][q * 4 + h * 2] = s1; part[arow][q * 4 + h * 2 + 1] = s2; }
        __syncthreads();   // barrier B

        f32x4 pt = *(const f32x4*)&part[arow][q * 4];
        float mean = (pt[0] + pt[2]) * (1.f / 128.f);
        float var  = (pt[1] + pt[3]) * (1.f / 128.f) - mean * mean;
        float rstd = rsqrtf(var + EPS_);
        const float* lgp = lng + l * HD_;
        const float* lbp = lnb + l * HD_;

        if (l < L_ - 1) {
            #pragma unroll
            for (int dm = 0; dm < 4; dm++) {
                int j = h * 64 + dm * 16 + lg * 4;
                float4 g  = *(const float4*)(lgp + j);
                float4 bb = *(const float4*)(lbp + j);
                bfv4 y;
                y[0] = (__bf16)((yv[dm][0] - mean) * rstd * g.x + bb.x);
                y[1] = (__bf16)((yv[dm][1] - mean) * rstd * g.y + bb.y);
                y[2] = (__bf16)((yv[dm][2] - mean) * rstd * g.z + bb.z);
                y[3] = (__bf16)((yv[dm][3] - mean) * rstd * g.w + bb.w);
                int ks2 = h * 2 + (dm >> 1);
                int ln2 = (((dm * 2 + (lg >> 1)) & 3) << 4) + l15;
                int g2 = (arow * 8 + qh * 4 + ks2) * 64 + ln2;
                *(bfv4*)&xs[g2 * 8 + half] = y;
            }
            __syncthreads();   // barrier C
        } else {
            #pragma unroll
            for (int dm = 0; dm < 4; dm++) {
                int j = h * 64 + dm * 16 + lg * 4;
                float4 g  = *(const float4*)(lgp + j);
                float4 bb = *(const float4*)(lbp + j);
                float4 w  = *(const float4*)(Wl + q * HD_ + j);
                head_partial = fmaf((yv[dm][0] - mean) * rstd * g.x + bb.x, w.x, head_partial);
                head_partial = fmaf((yv[dm][1] - mean) * rstd * g.y + bb.y, w.y, head_partial);
                head_partial = fmaf((yv[dm][2] - mean) * rstd * g.z + bb.z, w.z, head_partial);
                head_partial = fmaf((yv[dm][3] - mean) * rstd * g.w + bb.w, w.w, head_partial);
            }
        }
    }

    float* red = (float*)pf;
    red[tid] = head_partial;
    __syncthreads();
    if ((wid & 3) == 0) {
        int br = wid >> 2;
        int base = br * 256;
        float s = red[base + lane] + red[base + 64 + lane]
                + red[base + 128 + lane] + red[base + 192 + lane];
        #pragma unroll
        for (int off = 32; off; off >>= 1) s += __shfl_down(s, off);
        if (lane == 0) attnp[(int64_t)ablk * 2 + br] = s;
    }
}

// ---------------------------------------------------------------------------
extern "C" void kernel_launch(void* const* d_in, const int* in_sizes, int n_in,
                              void* d_out, int out_size, void* d_ws, size_t ws_size,
                              hipStream_t stream)
{
    const int*   tokens       = (const int*)  d_in[0];
    const int*   field_ids    = (const int*)  d_in[1];
    const float* word_emb     = (const float*)d_in[2];
    const float* W_tok        = (const float*)d_in[3];
    const float* field_tables = (const float*)d_in[4];
    const float* Wq           = (const float*)d_in[5];
    const float* Wk           = (const float*)d_in[6];
    const float* Wv           = (const float*)d_in[7];
    const float* Wres         = (const float*)d_in[8];
    const float* ln_g         = (const float*)d_in[9];
    const float* ln_b         = (const float*)d_in[10];
    const float* dnn_W1       = (const float*)d_in[11];
    const float* bn1_g        = (const float*)d_in[12];
    const float* bn1_b        = (const float*)d_in[13];
    const float* bn1_m        = (const float*)d_in[14];
    const float* bn1_v        = (const float*)d_in[15];
    const float* dnn_W2       = (const float*)d_in[16];
    const float* bn2_g        = (const float*)d_in[17];
    const float* bn2_b        = (const float*)d_in[18];
    const float* bn2_m        = (const float*)d_in[19];
    const float* bn2_v        = (const float*)d_in[20];
    const float* dnn_W3       = (const float*)d_in[21];
    const float* dnn_b3       = (const float*)d_in[22];
    const float* W_last       = (const float*)d_in[23];
    const float* b_last       = (const float*)d_in[24];
    float* out = (float*)d_out;

    const int64_t embN = (int64_t)B_ * F_ * E_;           // 16,777,216
    __bf16* embbf = (__bf16*)d_ws;                         // 32 MB
    float*  h3    = (float*)(embbf + embN);                // (layout spacer)
    __bf16* pkw   = (__bf16*)(h3 + (int64_t)B_ * 128);     // 384 KB
    __bf16* W1t   = pkw + 12 * 16384;                      // 8 MB
    __bf16* W2t   = W1t + (int64_t)1024 * 4096;            // 1 MB
    __bf16* W3t   = W2t + (int64_t)512 * 1024;             // 128 KB
    __bf16* h1bf  = W3t + (int64_t)128 * 512;              // 8 MB
    __bf16* h2bf  = h1bf + (int64_t)B_ * 1024;             // 4 MB
    float*  attnp = (float*)(h2bf + (int64_t)B_ * 512);    // 16 KB

    // PREP: pkw + W1t + embeddings (7136 blocks)
    prep_kernel<<<7136, 256, 0, stream>>>(
        Wq, Wk, Wv, Wres, pkw, dnn_W1, W1t,
        tokens, word_emb, W_tok, field_ids, field_tables, embbf);

    // MEGA: W1 GEMM (256) + W2t/W3t transposes (144) + attention (2048)
    mega_w1_attn_kernel<<<W1_BLOCKS_ + TR_BLOCKS_ + B_ / 2, 512, 0, stream>>>(
        embbf, W1t, h1bf, bn1_g, bn1_b, bn1_m, bn1_v,
        pkw, ln_g, ln_b, W_last, attnp, dnn_W2, W2t, dnn_W3, W3t);

    // W2
    gemm_bt_bf16<1, 0><<<dim3(32, 8), 256, 0, stream>>>(
        h1bf, W2t, h2bf, B_, 512, 1024, bn2_g, bn2_b, bn2_m, bn2_v);

    // W3 + head (fused)
    gemm_w3_head_kernel<<<32, 256, 0, stream>>>(
        h2bf, W3t, dnn_b3, W_last, attnp, b_last, out);
}

// Round 16
// 202.890 us; speedup vs baseline: 1.0333x; 1.0333x over previous
//
#include <hip/hip_runtime.h>
#include <hip/hip_bf16.h>
#include <cstdint>

#define B_  4096
#define T_  20
#define F_  32
#define E_  128
#define H_  2
#define D_  64
#define L_  3
#define HD_ 128
#define EPS_ 1e-5f

typedef __bf16 bfv8 __attribute__((ext_vector_type(8)));
typedef __bf16 bfv4 __attribute__((ext_vector_type(4)));
typedef float  f32x4 __attribute__((ext_vector_type(4)));

__device__ __forceinline__ f32x4 mfma16(bfv8 a, bfv8 b, f32x4 c) {
    return __builtin_amdgcn_mfma_f32_16x16x32_bf16(a, b, c, 0, 0, 0);
}

__device__ __forceinline__ void gload16(const __bf16* g, __bf16* l) {
    __builtin_amdgcn_global_load_lds(
        (const __attribute__((address_space(1))) void*)(g),
        (__attribute__((address_space(3))) void*)(l),
        16, 0, 0);
}

// ---------------------------------------------------------------------------
// 0. PREP kernel: attention-weight pack + W1 transpose + embeddings.
//    [0,96): pkw | [96,1120): W1t | [1120,3168): token emb | [3168,7136): field
// ---------------------------------------------------------------------------
__device__ void transpose_pack_body(const float* __restrict__ in,
                                    __bf16* __restrict__ out,
                                    int K, int N, int bx, int by)
{
    __shared__ float t[64][65];
    int k0 = bx * 64, n0 = by * 64;
    int r = threadIdx.x >> 4, c = (threadIdx.x & 15) * 4;
    for (int rr = r; rr < 64; rr += 16) {
        float4 v = *(const float4*)&in[(int64_t)(k0 + rr) * N + n0 + c];
        t[rr][c] = v.x; t[rr][c + 1] = v.y; t[rr][c + 2] = v.z; t[rr][c + 3] = v.w;
    }
    __syncthreads();
    for (int rr = r; rr < 64; rr += 16) {
        bfv4 o;
        o[0] = (__bf16)t[c + 0][rr];
        o[1] = (__bf16)t[c + 1][rr];
        o[2] = (__bf16)t[c + 2][rr];
        o[3] = (__bf16)t[c + 3][rr];
        *(bfv4*)&out[(int64_t)(n0 + rr) * K + k0 + c] = o;
    }
}

__global__ __launch_bounds__(256) void prep_kernel(
    const float* __restrict__ Wq, const float* __restrict__ Wk,
    const float* __restrict__ Wv, const float* __restrict__ Wres,
    __bf16* __restrict__ pkw,
    const float* __restrict__ dW1, __bf16* __restrict__ W1t,
    const int* __restrict__ tokens, const float* __restrict__ word_emb,
    const float* __restrict__ W_tok,
    const int* __restrict__ field_ids, const float* __restrict__ field_tables,
    __bf16* __restrict__ embbf)
{
    int id = blockIdx.x;
    if (id < 96) {
        int mi = id >> 3, tile = id & 7;
        int l = mi >> 2, p = mi & 3;
        const float* Wb = (p == 0 ? Wq : p == 1 ? Wk : p == 2 ? Wv : Wres) + l * 16384;
        int tid = threadIdx.x;
        int ks = tid >> 6, lane = tid & 63;
        int l15 = lane & 15, lgg = lane >> 4;
        const float* src = Wb + (ks * 32 + lgg * 8) * HD_ + tile * 16 + l15;
        __bf16* dst = pkw + (int64_t)mi * 16384 + ((tile * 4 + ks) * 64 + lane) * 8;
        #pragma unroll
        for (int t = 0; t < 8; t++) dst[t] = (__bf16)src[t * HD_];
    } else if (id < 1120) {
        int t = id - 96;
        transpose_pack_body(dW1, W1t, 4096, 1024, t & 63, t >> 6);
    } else if (id < 3168) {
        __shared__ float m[2][304];
        int half = threadIdx.x >> 7, t7 = threadIdx.x & 127;
        int b = (id - 1120) * 2 + half;
        float a0 = 0.f, a1 = 0.f, a2 = 0.f;
        const int* tb = tokens + b * T_;
        for (int t = 0; t < T_; t++) {
            const float* row = word_emb + (int64_t)tb[t] * 300;
            a0 += row[t7];
            a1 += row[t7 + 128];
            if (t7 < 44) a2 += row[t7 + 256];
        }
        m[half][t7]       = a0 * (1.f / T_);
        m[half][t7 + 128] = a1 * (1.f / T_);
        if (t7 < 44) m[half][t7 + 256] = a2 * (1.f / T_);
        __syncthreads();
        float s = 0.f;
        for (int e = 0; e < 300; e++) s = fmaf(m[half][e], W_tok[e * E_ + t7], s);
        embbf[(int64_t)b * (F_ * E_) + t7] = (__bf16)s;
    } else {
        int64_t base = (int64_t)(id - 3168) * 1024 + threadIdx.x;
        #pragma unroll
        for (int u = 0; u < 4; u++) {
            int64_t idx = base + u * 256;
            int c = (int)(idx & 31);
            int64_t tmp = idx >> 5;
            int f = (int)(tmp % 31);
            int b = (int)(tmp / 31);
            int ident = field_ids[b * 31 + f];
            const float4* src = (const float4*)field_tables;
            float4 val = src[(int64_t)(f * 1000 + ident) * 32 + c];
            bfv4 o;
            o[0] = (__bf16)val.x; o[1] = (__bf16)val.y;
            o[2] = (__bf16)val.z; o[3] = (__bf16)val.w;
            *(bfv4*)&embbf[(int64_t)b * 4096 + (1 + f) * 128 + c * 4] = o;
        }
    }
}

// ---------------------------------------------------------------------------
// 3b. 128x64-tile bf16 MFMA GEMM (W2).
// ---------------------------------------------------------------------------
template <int OUTBF, int EPI>
__global__ __launch_bounds__(256) void gemm_bt_bf16(
    const __bf16* __restrict__ A, const __bf16* __restrict__ Bt,
    void* __restrict__ Cout, int M, int N, int K,
    const float* __restrict__ gp, const float* __restrict__ bp,
    const float* __restrict__ mp, const float* __restrict__ vp)
{
    __shared__ __bf16 As[128 * 64];
    __shared__ __bf16 Bs[64 * 64];
    const int tid = threadIdx.x;
    const int wid = tid >> 6, lane = tid & 63;
    const int l15 = lane & 15, lg = lane >> 4;
    const int wr = wid >> 1, wc = wid & 1;
    const int bm = blockIdx.x, bn = blockIdx.y;

    const int srow = lane >> 3, sp = lane & 7;
    const __bf16* Ag[4]; const __bf16* Bg[2];
    __bf16* Ad[4]; __bf16* Bd[2];
    #pragma unroll
    for (int ga = 0; ga < 4; ga++) {
        int row = wid * 32 + ga * 8 + srow;
        int slot = sp ^ (row & 7);
        Ag[ga] = A + (int64_t)(bm * 128 + row) * K + slot * 8;
        Ad[ga] = &As[(wid * 32 + ga * 8) * 64];
    }
    #pragma unroll
    for (int gb = 0; gb < 2; gb++) {
        int row = wid * 16 + gb * 8 + srow;
        int slot = sp ^ (row & 7);
        Bg[gb] = Bt + (int64_t)(bn * 64 + row) * K + slot * 8;
        Bd[gb] = &Bs[(wid * 16 + gb * 8) * 64];
    }

    int ar[2][4], br2[2][2];
    #pragma unroll
    for (int ks = 0; ks < 2; ks++) {
        #pragma unroll
        for (int mi = 0; mi < 4; mi++) {
            int row = wr * 64 + mi * 16 + l15;
            ar[ks][mi] = row * 64 + (((ks * 4 + lg) ^ (row & 7)) * 8);
        }
        #pragma unroll
        for (int ni = 0; ni < 2; ni++) {
            int row = wc * 32 + ni * 16 + l15;
            br2[ks][ni] = row * 64 + (((ks * 4 + lg) ^ (row & 7)) * 8);
        }
    }

    f32x4 acc[4][2];
    #pragma unroll
    for (int mi = 0; mi < 4; mi++)
        #pragma unroll
        for (int ni = 0; ni < 2; ni++) acc[mi][ni] = (f32x4){0.f, 0.f, 0.f, 0.f};

    for (int k0 = 0; k0 < K; k0 += 64) {
        #pragma unroll
        for (int ga = 0; ga < 4; ga++) gload16(Ag[ga] + k0, Ad[ga]);
        #pragma unroll
        for (int gb = 0; gb < 2; gb++) gload16(Bg[gb] + k0, Bd[gb]);
        __syncthreads();
        #pragma unroll
        for (int ks = 0; ks < 2; ks++) {
            bfv8 af[4], bf2[2];
            #pragma unroll
            for (int mi = 0; mi < 4; mi++) af[mi] = *(const bfv8*)&As[ar[ks][mi]];
            #pragma unroll
            for (int ni = 0; ni < 2; ni++) bf2[ni] = *(const bfv8*)&Bs[br2[ks][ni]];
            #pragma unroll
            for (int mi = 0; mi < 4; mi++)
                #pragma unroll
                for (int ni = 0; ni < 2; ni++)
                    acc[mi][ni] = mfma16(af[mi], bf2[ni], acc[mi][ni]);
        }
        __syncthreads();
    }

    float inv[2], sh[2];
    #pragma unroll
    for (int ni = 0; ni < 2; ni++) {
        int col = bn * 64 + wc * 32 + ni * 16 + l15;
        if constexpr (EPI == 0) {
            float iv = rsqrtf(vp[col] + EPS_) * gp[col];
            inv[ni] = iv;
            sh[ni] = bp[col] - mp[col] * iv;
        } else {
            inv[ni] = 1.f;
            sh[ni] = bp[col];
        }
    }
    #pragma unroll
    for (int mi = 0; mi < 4; mi++)
        #pragma unroll
        for (int ni = 0; ni < 2; ni++) {
            int col = bn * 64 + wc * 32 + ni * 16 + l15;
            #pragma unroll
            for (int r = 0; r < 4; r++) {
                int row = bm * 128 + wr * 64 + mi * 16 + lg * 4 + r;
                float y = fmaf(acc[mi][ni][r], inv[ni], sh[ni]);
                if constexpr (EPI == 0) y = fmaxf(y, 0.f);
                if constexpr (OUTBF)
                    ((__bf16*)Cout)[(int64_t)row * N + col] = (__bf16)y;
                else
                    ((float*)Cout)[(int64_t)row * N + col] = y;
            }
        }
}

// ---------------------------------------------------------------------------
// 3c. W3 GEMM + head, fused. 128x128 tile, 4 waves, K=512, grid=32.
// ---------------------------------------------------------------------------
__global__ __launch_bounds__(256) void gemm_w3_head_kernel(
    const __bf16* __restrict__ A, const __bf16* __restrict__ Bt,
    const float* __restrict__ b3, const float* __restrict__ Wl,
    const float* __restrict__ attnp, const float* __restrict__ bl,
    float* __restrict__ out)
{
    __shared__ __bf16 As[128 * 64];
    __shared__ __bf16 Bs[128 * 64];
    __shared__ float  hp[128][2];
    const int tid = threadIdx.x;
    const int wid = tid >> 6, lane = tid & 63;
    const int l15 = lane & 15, lg = lane >> 4;
    const int wr = wid >> 1, wc = wid & 1;
    const int bm = blockIdx.x;
    const int K = 512;

    const int srow = lane >> 3, sp = lane & 7;
    const __bf16* Ag[4]; const __bf16* Bg[4];
    __bf16* Ad[4]; __bf16* Bd[4];
    #pragma unroll
    for (int ga = 0; ga < 4; ga++) {
        int row = wid * 32 + ga * 8 + srow;
        int slot = sp ^ (row & 7);
        Ag[ga] = A  + (int64_t)(bm * 128 + row) * K + slot * 8;
        Bg[ga] = Bt + (int64_t)row * K + slot * 8;
        Ad[ga] = &As[(wid * 32 + ga * 8) * 64];
        Bd[ga] = &Bs[(wid * 32 + ga * 8) * 64];
    }

    int ar[2][4], br[2][4];
    #pragma unroll
    for (int ks = 0; ks < 2; ks++) {
        #pragma unroll
        for (int mi = 0; mi < 4; mi++) {
            int rowa = wr * 64 + mi * 16 + l15;
            ar[ks][mi] = rowa * 64 + (((ks * 4 + lg) ^ (rowa & 7)) * 8);
            int rowb = wc * 64 + mi * 16 + l15;
            br[ks][mi] = rowb * 64 + (((ks * 4 + lg) ^ (rowb & 7)) * 8);
        }
    }

    f32x4 acc[4][4];
    #pragma unroll
    for (int mi = 0; mi < 4; mi++)
        #pragma unroll
        for (int ni = 0; ni < 4; ni++) acc[mi][ni] = (f32x4){0.f, 0.f, 0.f, 0.f};

    for (int k0 = 0; k0 < K; k0 += 64) {
        #pragma unroll
        for (int ga = 0; ga < 4; ga++) gload16(Ag[ga] + k0, Ad[ga]);
        #pragma unroll
        for (int ga = 0; ga < 4; ga++) gload16(Bg[ga] + k0, Bd[ga]);
        __syncthreads();
        #pragma unroll
        for (int ks = 0; ks < 2; ks++) {
            bfv8 af[4], bf[4];
            #pragma unroll
            for (int mi = 0; mi < 4; mi++) af[mi] = *(const bfv8*)&As[ar[ks][mi]];
            #pragma unroll
            for (int ni = 0; ni < 4; ni++) bf[ni] = *(const bfv8*)&Bs[br[ks][ni]];
            #pragma unroll
            for (int mi = 0; mi < 4; mi++)
                #pragma unroll
                for (int ni = 0; ni < 4; ni++)
                    acc[mi][ni] = mfma16(af[mi], bf[ni], acc[mi][ni]);
        }
        __syncthreads();
    }

    float wl[4], bb[4];
    #pragma unroll
    for (int ni = 0; ni < 4; ni++) {
        int col = wc * 64 + ni * 16 + l15;
        wl[ni] = Wl[4096 + col];
        bb[ni] = b3[col];
    }
    #pragma unroll
    for (int mi = 0; mi < 4; mi++) {
        #pragma unroll
        for (int r = 0; r < 4; r++) {
            float p = (acc[mi][0][r] + bb[0]) * wl[0]
                    + (acc[mi][1][r] + bb[1]) * wl[1]
                    + (acc[mi][2][r] + bb[2]) * wl[2]
                    + (acc[mi][3][r] + bb[3]) * wl[3];
            p += __shfl_xor(p, 1);
            p += __shfl_xor(p, 2);
            p += __shfl_xor(p, 4);
            p += __shfl_xor(p, 8);
            if (l15 == 0) hp[wr * 64 + mi * 16 + lg * 4 + r][wc] = p;
        }
    }
    __syncthreads();
    if (tid < 128) {
        int64_t b0 = (int64_t)bm * 128 + tid;
        float s = hp[tid][0] + hp[tid][1] + attnp[b0] + bl[0];
        out[b0] = 1.f / (1.f + __expf(-s));
    }
}

// ---------------------------------------------------------------------------
// MEGA kernel: [0,256) W1 GEMM | [256,400) W2t/W3t transpose |
//              [400,2448) fused 3-layer attention (head -> attnp).
//              (round-14 verified configuration, NO setprio)
// ---------------------------------------------------------------------------
#define W1_BLOCKS_ 256
#define TR_BLOCKS_ 144

__global__ __launch_bounds__(512, 4) void mega_w1_attn_kernel(
    const __bf16* __restrict__ embbf, const __bf16* __restrict__ W1t,
    __bf16* __restrict__ h1bf,
    const float* __restrict__ bn1g, const float* __restrict__ bn1b,
    const float* __restrict__ bn1m, const float* __restrict__ bn1v,
    const __bf16* __restrict__ pkw,
    const float* __restrict__ lng, const float* __restrict__ lnb,
    const float* __restrict__ Wl, float* __restrict__ attnp,
    const float* __restrict__ dW2, __bf16* __restrict__ W2t,
    const float* __restrict__ dW3, __bf16* __restrict__ W3t)
{
    __shared__ __bf16 smem[8192 * 4 + 4096];
    __shared__ float  part[2][128];

    const int tid = threadIdx.x;
    const int wid = tid >> 6, lane = tid & 63;
    const int l15 = lane & 15, lg = lane >> 4;

    if (blockIdx.x < W1_BLOCKS_) {
        // ================= W1 GEMM branch: 128x128 tile, 8 waves ===========
        __bf16* As = smem;
        __bf16* Bs = smem + 8192;
        const int wr = wid >> 2, wc = wid & 3;
        const int bm = blockIdx.x >> 3, bn = blockIdx.x & 7;
        const int K = 4096, N = 1024;

        const int srow = lane >> 3, sp = lane & 7;
        const __bf16* Ag[2]; const __bf16* Bg[2];
        __bf16* Ad[2]; __bf16* Bd[2];
        #pragma unroll
        for (int c = 0; c < 2; c++) {
            int rbase = wid * 16 + c * 8;
            int row = rbase + srow;
            int slot = sp ^ (row & 7);
            Ag[c] = embbf + (int64_t)(bm * 128 + row) * K + slot * 8;
            Bg[c] = W1t   + (int64_t)(bn * 128 + row) * K + slot * 8;
            Ad[c] = &As[rbase * 64];
            Bd[c] = &Bs[rbase * 64];
        }

        int ar[2][4], br[2][2];
        #pragma unroll
        for (int ks = 0; ks < 2; ks++) {
            #pragma unroll
            for (int mi = 0; mi < 4; mi++) {
                int rowa = wr * 64 + mi * 16 + l15;
                ar[ks][mi] = rowa * 64 + (((ks * 4 + lg) ^ (rowa & 7)) * 8);
            }
            #pragma unroll
            for (int ni = 0; ni < 2; ni++) {
                int rowb = wc * 32 + ni * 16 + l15;
                br[ks][ni] = rowb * 64 + (((ks * 4 + lg) ^ (rowb & 7)) * 8);
            }
        }

        f32x4 acc[4][2];
        #pragma unroll
        for (int mi = 0; mi < 4; mi++)
            #pragma unroll
            for (int ni = 0; ni < 2; ni++) acc[mi][ni] = (f32x4){0.f, 0.f, 0.f, 0.f};

        for (int k0 = 0; k0 < K; k0 += 64) {
            #pragma unroll
            for (int c = 0; c < 2; c++) gload16(Ag[c] + k0, Ad[c]);
            #pragma unroll
            for (int c = 0; c < 2; c++) gload16(Bg[c] + k0, Bd[c]);
            __syncthreads();
            #pragma unroll
            for (int ks = 0; ks < 2; ks++) {
                bfv8 af[4], bf[2];
                #pragma unroll
                for (int mi = 0; mi < 4; mi++) af[mi] = *(const bfv8*)&As[ar[ks][mi]];
                #pragma unroll
                for (int ni = 0; ni < 2; ni++) bf[ni] = *(const bfv8*)&Bs[br[ks][ni]];
                #pragma unroll
                for (int mi = 0; mi < 4; mi++)
                    #pragma unroll
                    for (int ni = 0; ni < 2; ni++)
                        acc[mi][ni] = mfma16(af[mi], bf[ni], acc[mi][ni]);
            }
            __syncthreads();
        }

        float inv[2], sh[2];
        #pragma unroll
        for (int ni = 0; ni < 2; ni++) {
            int col = bn * 128 + wc * 32 + ni * 16 + l15;
            float iv = rsqrtf(bn1v[col] + EPS_) * bn1g[col];
            inv[ni] = iv;
            sh[ni] = bn1b[col] - bn1m[col] * iv;
        }
        #pragma unroll
        for (int mi = 0; mi < 4; mi++)
            #pragma unroll
            for (int ni = 0; ni < 2; ni++) {
                int col = bn * 128 + wc * 32 + ni * 16 + l15;
                #pragma unroll
                for (int r = 0; r < 4; r++) {
                    int row = bm * 128 + wr * 64 + mi * 16 + lg * 4 + r;
                    float y = fmaxf(fmaf(acc[mi][ni][r], inv[ni], sh[ni]), 0.f);
                    h1bf[(int64_t)row * N + col] = (__bf16)y;
                }
            }
        return;
    }

    if (blockIdx.x < W1_BLOCKS_ + TR_BLOCKS_) {
        // ================= W2t / W3t transpose branch (512 threads) ========
        float* t = (float*)smem;
        int tb = blockIdx.x - W1_BLOCKS_;
        const float* in; __bf16* outp; int K, N, bx, by;
        if (tb < 128) { in = dW2; outp = W2t; K = 1024; N = 512; bx = tb & 15; by = tb >> 4; }
        else          { tb -= 128; in = dW3; outp = W3t; K = 512; N = 128; bx = tb & 7; by = tb >> 3; }
        int k0 = bx * 64, n0 = by * 64;
        int r = tid >> 4, c = (tid & 15) * 4;
        for (int rr = r; rr < 64; rr += 32) {
            float4 v = *(const float4*)&in[(int64_t)(k0 + rr) * N + n0 + c];
            t[rr * 65 + c] = v.x; t[rr * 65 + c + 1] = v.y;
            t[rr * 65 + c + 2] = v.z; t[rr * 65 + c + 3] = v.w;
        }
        __syncthreads();
        for (int rr = r; rr < 64; rr += 32) {
            bfv4 o;
            o[0] = (__bf16)t[(c + 0) * 65 + rr];
            o[1] = (__bf16)t[(c + 1) * 65 + rr];
            o[2] = (__bf16)t[(c + 2) * 65 + rr];
            o[3] = (__bf16)t[(c + 3) * 65 + rr];
            *(bfv4*)&outp[(int64_t)(n0 + rr) * K + k0 + c] = o;
        }
        return;
    }

    // ================= attention branch (round-10 verified body) ===========
    const int ablk = blockIdx.x - (W1_BLOCKS_ + TR_BLOCKS_);
    __bf16* xs  = smem;
    __bf16* qf  = smem + 8192;
    __bf16* kf  = smem + 16384;
    __bf16* vtf = smem + 24576;
    __bf16* pf  = smem + 32768;

    const int arow = wid >> 2, h = (wid >> 1) & 1, qh = wid & 1;
    const int q = qh * 16 + l15;
    const int half = (lg & 1) * 4;

    {
        const __bf16* src = embbf + (int64_t)ablk * 8192;
        #pragma unroll
        for (int u = 0; u < 2; u++) {
            int g = u * 512 + tid;
            int ln = g & 63;
            int fld = (((g >> 8) & 1) << 4) + (ln & 15);
            int e0 = ((g >> 6) & 3) * 32 + (ln >> 4) * 8;
            int br = g >> 9;
            bfv8 v = *(const bfv8*)&src[br * 4096 + fld * 128 + e0];
            *(bfv8*)&xs[g * 8] = v;
        }
    }
    __syncthreads();

    float head_partial = 0.f;

    for (int l = 0; l < L_; l++) {
        #pragma unroll 1
        for (int cc = 0; cc < 3; cc++) {
            const int col = wid * 3 + cc;
            const int mat = col >> 3, m = col & 7;
            const __bf16* W = pkw + (l * 4 + mat) * 16384;
            bfv8 wf[4];
            #pragma unroll
            for (int ks = 0; ks < 4; ks++)
                wf[ks] = *(const bfv8*)(W + ((m * 4 + ks) * 64 + lane) * 8);
            f32x4 pc[4];
            #pragma unroll
            for (int i = 0; i < 4; i++) pc[i] = (f32x4){0.f, 0.f, 0.f, 0.f};

            if (mat == 2) {
                #pragma unroll
                for (int i = 0; i < 4; i++) {
                    int gbase = ((i >> 1) * 8 + (i & 1) * 4) * 64;
                    #pragma unroll
                    for (int ks = 0; ks < 4; ks++) {
                        bfv8 xv = *(const bfv8*)&xs[(gbase + ks * 64 + lane) * 8];
                        pc[i] = mfma16(xv, wf[ks], pc[i]);
                    }
                }
            } else {
                #pragma unroll
                for (int i = 0; i < 4; i++) {
                    int gbase = ((i >> 1) * 8 + (i & 1) * 4) * 64;
                    #pragma unroll
                    for (int ks = 0; ks < 4; ks++) {
                        bfv8 xv = *(const bfv8*)&xs[(gbase + ks * 64 + lane) * 8];
                        pc[i] = mfma16(wf[ks], xv, pc[i]);
                    }
                }
            }

            if (mat == 0) {
                const int ln2 = ((((m << 1) + (lg >> 1)) & 3) << 4) + l15;
                #pragma unroll
                for (int i = 0; i < 4; i++) {
                    bfv4 v4;
                    #pragma unroll
                    for (int r = 0; r < 4; r++) v4[r] = (__bf16)(pc[i][r] * 0.125f);
                    int g = ((i >> 1) * 8 + (i & 1) * 4 + (m >> 1)) * 64 + ln2;
                    *(bfv4*)&qf[g * 8 + half] = v4;
                }
            } else if (mat == 1) {
                const int ln2 = ((((m << 1) + (lg >> 1)) & 3) << 4) + l15;
                #pragma unroll
                for (int i = 0; i < 4; i++) {
                    bfv4 v4;
                    #pragma unroll
                    for (int r = 0; r < 4; r++) v4[r] = (__bf16)pc[i][r];
                    int g = ((i >> 1) * 8 + (i & 1) * 4 + (m >> 1)) * 64 + ln2;
                    *(bfv4*)&kf[g * 8 + half] = v4;
                }
            } else {
                #pragma unroll
                for (int i = 0; i < 4; i++) {
                    bfv4 v4;
                    #pragma unroll
                    for (int r = 0; r < 4; r++) v4[r] = (__bf16)pc[i][r];
                    int lnv = ((((i & 1) * 2 + (lg >> 1)) & 3) << 4) + l15;
                    int g = ((i >> 1) * 8 + m) * 64 + lnv;
                    *(bfv4*)&vtf[g * 8 + half] = v4;
                }
            }
        }
        __syncthreads();   // barrier A

        const __bf16* Wr = pkw + (l * 4 + 3) * 16384;
        bfv8 wr0[4], wr1[4], wr2[4], wr3[4];
        #pragma unroll
        for (int ks = 0; ks < 4; ks++) {
            wr0[ks] = *(const bfv8*)(Wr + (((h * 4 + 0) * 4 + ks) * 64 + lane) * 8);
            wr1[ks] = *(const bfv8*)(Wr + (((h * 4 + 1) * 4 + ks) * 64 + lane) * 8);
            wr2[ks] = *(const bfv8*)(Wr + (((h * 4 + 2) * 4 + ks) * 64 + lane) * 8);
            wr3[ks] = *(const bfv8*)(Wr + (((h * 4 + 3) * 4 + ks) * 64 + lane) * 8);
        }

        f32x4 sc2[2] = {(f32x4){0.f, 0.f, 0.f, 0.f}, (f32x4){0.f, 0.f, 0.f, 0.f}};
        #pragma unroll
        for (int ksp = 0; ksp < 2; ksp++) {
            int dks = h * 2 + ksp;
            bfv8 qb = *(const bfv8*)&qf[((arow * 8 + qh * 4 + dks) * 64 + lane) * 8];
            #pragma unroll
            for (int km = 0; km < 2; km++) {
                bfv8 kb = *(const bfv8*)&kf[((arow * 8 + km * 4 + dks) * 64 + lane) * 8];
                sc2[km] = mfma16(kb, qb, sc2[km]);
            }
        }

        f32x4 macc[4];
        {
            bfv8 xr[4];
            #pragma unroll
            for (int ks = 0; ks < 4; ks++)
                xr[ks] = *(const bfv8*)&xs[((arow * 8 + qh * 4 + ks) * 64 + lane) * 8];
            macc[0] = (f32x4){0.f, 0.f, 0.f, 0.f};
            macc[1] = (f32x4){0.f, 0.f, 0.f, 0.f};
            macc[2] = (f32x4){0.f, 0.f, 0.f, 0.f};
            macc[3] = (f32x4){0.f, 0.f, 0.f, 0.f};
            #pragma unroll
            for (int ks = 0; ks < 4; ks++) {
                macc[0] = mfma16(wr0[ks], xr[ks], macc[0]);
                macc[1] = mfma16(wr1[ks], xr[ks], macc[1]);
                macc[2] = mfma16(wr2[ks], xr[ks], macc[2]);
                macc[3] = mfma16(wr3[ks], xr[ks], macc[3]);
            }
        }

        float mx = -1e30f;
        #pragma unroll
        for (int km = 0; km < 2; km++)
            #pragma unroll
            for (int r = 0; r < 4; r++) mx = fmaxf(mx, sc2[km][r]);
        mx = fmaxf(mx, __shfl_xor(mx, 16));
        mx = fmaxf(mx, __shfl_xor(mx, 32));
        float pv[2][4];
        float sum = 0.f;
        #pragma unroll
        for (int km = 0; km < 2; km++)
            #pragma unroll
            for (int r = 0; r < 4; r++) {
                float e = __expf(sc2[km][r] - mx);
                pv[km][r] = e; sum += e;
            }
        sum += __shfl_xor(sum, 16);
        sum += __shfl_xor(sum, 32);
        float inv = 1.f / sum;

        __bf16* pw = pf + wid * 512;
        #pragma unroll
        for (int km = 0; km < 2; km++) {
            int ln2 = (((km * 2 + (lg >> 1)) & 3) << 4) + l15;
            bfv4 v4;
            #pragma unroll
            for (int r = 0; r < 4; r++) v4[r] = (__bf16)(pv[km][r] * inv);
            *(bfv4*)&pw[ln2 * 8 + half] = v4;
        }
        bfv8 pb = *(const bfv8*)&pw[lane * 8];
        #pragma unroll
        for (int dm = 0; dm < 4; dm++) {
            bfv8 va = *(const bfv8*)&vtf[((arow * 8 + h * 4 + dm) * 64 + lane) * 8];
            macc[dm] = mfma16(va, pb, macc[dm]);
        }

        float yv[4][4];
        float s1 = 0.f, s2 = 0.f;
        #pragma unroll
        for (int dm = 0; dm < 4; dm++) {
            #pragma unroll
            for (int r = 0; r < 4; r++) {
                float v = fmaxf(macc[dm][r], 0.f);
                yv[dm][r] = v;
                s1 += v; s2 += v * v;
            }
        }
        s1 += __shfl_xor(s1, 16); s1 += __shfl_xor(s1, 32);
        s2 += __shfl_xor(s2, 16); s2 += __shfl_xor(s2, 32);
        if (lg == 0) { part[arow][q * 4 + h * 2] = s1; part[arow][q * 4 + h * 2 + 1] = s2; }
        __syncthreads();   // barrier B

        f32x4 pt = *(const f32x4*)&part[arow][q * 4];
        float mean = (pt[0] + pt[2]) * (1.f / 128.f);
        float var  = (pt[1] + pt[3]) * (1.f / 128.f) - mean * mean;
        float rstd = rsqrtf(var + EPS_);
        const float* lgp = lng + l * HD_;
        const float* lbp = lnb + l * HD_;

        if (l < L_ - 1) {
            #pragma unroll
            for (int dm = 0; dm < 4; dm++) {
                int j = h * 64 + dm * 16 + lg * 4;
                float4 g  = *(const float4*)(lgp + j);
                float4 bb = *(const float4*)(lbp + j);
                bfv4 y;
                y[0] = (__bf16)((yv[dm][0] - mean) * rstd * g.x + bb.x);
                y[1] = (__bf16)((yv[dm][1] - mean) * rstd * g.y + bb.y);
                y[2] = (__bf16)((yv[dm][2] - mean) * rstd * g.z + bb.z);
                y[3] = (__bf16)((yv[dm][3] - mean) * rstd * g.w + bb.w);
                int ks2 = h * 2 + (dm >> 1);
                int ln2 = (((dm * 2 + (lg >> 1)) & 3) << 4) + l15;
                int g2 = (arow * 8 + qh * 4 + ks2) * 64 + ln2;
                *(bfv4*)&xs[g2 * 8 + half] = y;
            }
            __syncthreads();   // barrier C
        } else {
            #pragma unroll
            for (int dm = 0; dm < 4; dm++) {
                int j = h * 64 + dm * 16 + lg * 4;
                float4 g  = *(const float4*)(lgp + j);
                float4 bb = *(const float4*)(lbp + j);
                float4 w  = *(const float4*)(Wl + q * HD_ + j);
                head_partial = fmaf((yv[dm][0] - mean) * rstd * g.x + bb.x, w.x, head_partial);
                head_partial = fmaf((yv[dm][1] - mean) * rstd * g.y + bb.y, w.y, head_partial);
                head_partial = fmaf((yv[dm][2] - mean) * rstd * g.z + bb.z, w.z, head_partial);
                head_partial = fmaf((yv[dm][3] - mean) * rstd * g.w + bb.w, w.w, head_partial);
            }
        }
    }

    float* red = (float*)pf;
    red[tid] = head_partial;
    __syncthreads();
    if ((wid & 3) == 0) {
        int br = wid >> 2;
        int base = br * 256;
        float s = red[base + lane] + red[base + 64 + lane]
                + red[base + 128 + lane] + red[base + 192 + lane];
        #pragma unroll
        for (int off = 32; off; off >>= 1) s += __shfl_down(s, off);
        if (lane == 0) attnp[(int64_t)ablk * 2 + br] = s;
    }
}

// ---------------------------------------------------------------------------
extern "C" void kernel_launch(void* const* d_in, const int* in_sizes, int n_in,
                              void* d_out, int out_size, void* d_ws, size_t ws_size,
                              hipStream_t stream)
{
    const int*   tokens       = (const int*)  d_in[0];
    const int*   field_ids    = (const int*)  d_in[1];
    const float* word_emb     = (const float*)d_in[2];
    const float* W_tok        = (const float*)d_in[3];
    const float* field_tables = (const float*)d_in[4];
    const float* Wq           = (const float*)d_in[5];
    const float* Wk           = (const float*)d_in[6];
    const float* Wv           = (const float*)d_in[7];
    const float* Wres         = (const float*)d_in[8];
    const float* ln_g         = (const float*)d_in[9];
    const float* ln_b         = (const float*)d_in[10];
    const float* dnn_W1       = (const float*)d_in[11];
    const float* bn1_g        = (const float*)d_in[12];
    const float* bn1_b        = (const float*)d_in[13];
    const float* bn1_m        = (const float*)d_in[14];
    const float* bn1_v        = (const float*)d_in[15];
    const float* dnn_W2       = (const float*)d_in[16];
    const float* bn2_g        = (const float*)d_in[17];
    const float* bn2_b        = (const float*)d_in[18];
    const float* bn2_m        = (const float*)d_in[19];
    const float* bn2_v        = (const float*)d_in[20];
    const float* dnn_W3       = (const float*)d_in[21];
    const float* dnn_b3       = (const float*)d_in[22];
    const float* W_last       = (const float*)d_in[23];
    const float* b_last       = (const float*)d_in[24];
    float* out = (float*)d_out;

    const int64_t embN = (int64_t)B_ * F_ * E_;           // 16,777,216
    __bf16* embbf = (__bf16*)d_ws;                         // 32 MB
    float*  h3    = (float*)(embbf + embN);                // (layout spacer)
    __bf16* pkw   = (__bf16*)(h3 + (int64_t)B_ * 128);     // 384 KB
    __bf16* W1t   = pkw + 12 * 16384;                      // 8 MB
    __bf16* W2t   = W1t + (int64_t)1024 * 4096;            // 1 MB
    __bf16* W3t   = W2t + (int64_t)512 * 1024;             // 128 KB
    __bf16* h1bf  = W3t + (int64_t)128 * 512;              // 8 MB
    __bf16* h2bf  = h1bf + (int64_t)B_ * 1024;             // 4 MB
    float*  attnp = (float*)(h2bf + (int64_t)B_ * 512);    // 16 KB

    // PREP: pkw + W1t + embeddings (7136 blocks)
    prep_kernel<<<7136, 256, 0, stream>>>(
        Wq, Wk, Wv, Wres, pkw, dnn_W1, W1t,
        tokens, word_emb, W_tok, field_ids, field_tables, embbf);

    // MEGA: W1 GEMM (256) + W2t/W3t transposes (144) + attention (2048)
    mega_w1_attn_kernel<<<W1_BLOCKS_ + TR_BLOCKS_ + B_ / 2, 512, 0, stream>>>(
        embbf, W1t, h1bf, bn1_g, bn1_b, bn1_m, bn1_v,
        pkw, ln_g, ln_b, W_last, attnp, dnn_W2, W2t, dnn_W3, W3t);

    // W2
    gemm_bt_bf16<1, 0><<<dim3(32, 8), 256, 0, stream>>>(
        h1bf, W2t, h2bf, B_, 512, 1024, bn2_g, bn2_b, bn2_m, bn2_v);

    // W3 + head (fused)
    gemm_w3_head_kernel<<<32, 256, 0, stream>>>(
        h2bf, W3t, dnn_b3, W_last, attnp, b_last, out);
}